// Round 9
// baseline (104.944 us; speedup 1.0000x reference)
//
#include <hip/hip_runtime.h>
#include <math.h>

#define IMH 512
#define IMW 512
#define RB    8     // output rows per wave-band
#define NBAND 64    // IMH / RB

typedef __attribute__((ext_vector_type(4))) float f32x4;

__device__ __forceinline__ int reflect_i(int v, int n) {
    if (v < 0) v = -v;
    if (v >= n) v = 2 * n - 2 - v;
    return v;
}
// branchless row reflect (valid for y in [-(IMH-1), 2*IMH-2])
__device__ __forceinline__ int reflect_row(int y) {
    int a = y < 0 ? -y : y;
    int b = 2 * IMH - 2 - a;
    return a < b ? a : b;
}
// DPP wave shifts (VALU pipe). 0x138=wave_shr1 (lane i <- i-1), 0x130=wave_shl1.
__device__ __forceinline__ float dpp_shr1(float x) {
    int i = __float_as_int(x);
    return __int_as_float(__builtin_amdgcn_update_dpp(i, i, 0x138, 0xF, 0xF, false));
}
__device__ __forceinline__ float dpp_shl1(float x) {
    int i = __float_as_int(x);
    return __int_as_float(__builtin_amdgcn_update_dpp(i, i, 0x130, 0xF, 0xF, false));
}

// R9 theory: per-step stall ~6000cy is config-invariant (R0/R5/R8) -> not HBM
// latency, not occupancy. Candidate: I$ thrash from ~50KB fully-unrolled text
// (16 vstep instances x 2 vec4 strips + unrolled scalar) vs 32KB I$.
// Fix: ONE rolled loop body per path. Depth-4 slots kept live via explicit
// register ROTATION (all compile-time indices -> registers, no scratch);
// phase gates become runtime uniform branches (s_cbranch, no divergence);
// strips A/B share a single inlined call site (runtime isA/c0).

__device__ __forceinline__ void vload(const float* __restrict__ p, int ro, int cx0,
                                      bool a0, float r[4]) {
    if (a0) {   // strip-A lane0: cols -4..-1 -> reflect -> 4,3,2,1
        r[0] = p[ro + 4]; r[1] = p[ro + 3]; r[2] = p[ro + 2]; r[3] = p[ro + 1];
    } else {
        f32x4 v = *reinterpret_cast<const f32x4*>(p + ro + cx0);
        r[0] = v.x; r[1] = v.y; r[2] = v.z; r[3] = v.w;
    }
}

__device__ __forceinline__ void run_band_v4(const float* __restrict__ p0,
                                            const float* __restrict__ p1,
                                            const float* __restrict__ p2,
                                            float* __restrict__ outp,
                                            int y0, int c0, int lane, bool isA) {
    const float w0 = 0.05448868f, w1 = 0.24420134f, w2 = 0.40261995f;
    const int cx0 = c0 + 4 * lane;
    const bool a0 = isA && (lane == 0);
    const bool clampL = isA && (lane == 1);   // owns col 0 -> sobel edge clamp
    const bool storeok = isA ? (lane >= 1 && lane <= 62) : (lane >= 1 && lane <= 61);

    // depth-4 rolling slots (rotated each step; indices all compile-time)
    float r0[4], r1[4], r2[4], r3[4];
    float g0[4], g1[4], g2[4], g3[4];
    float c0b[4], c1b[4], c2b[4], c3b[4];
    // pipeline rings
    float h0[4], h1[4], h2[4], h3[4];
    float b1[4], b0[4], b1L = 0, b1R = 0, b0L = 0, b0R = 0;
    float m1[4], m0[4], m1L = 0, m1R = 0, m0L = 0, m0R = 0;
    float gxp[4], gyp[4];
    #pragma unroll
    for (int j = 0; j < 4; ++j) {
        h0[j] = h1[j] = h2[j] = h3[j] = 0.0f;
        b1[j] = b0[j] = 0.0f; m1[j] = m0[j] = 0.0f;
        gxp[j] = gyp[j] = 0.0f;
    }
    {
        int ro;
        ro = reflect_row(y0 - 4) * IMW;
        vload(p0, ro, cx0, a0, r0); vload(p1, ro, cx0, a0, g0); vload(p2, ro, cx0, a0, c0b);
        ro = reflect_row(y0 - 3) * IMW;
        vload(p0, ro, cx0, a0, r1); vload(p1, ro, cx0, a0, g1); vload(p2, ro, cx0, a0, c1b);
        ro = reflect_row(y0 - 2) * IMW;
        vload(p0, ro, cx0, a0, r2); vload(p1, ro, cx0, a0, g2); vload(p2, ro, cx0, a0, c2b);
        ro = reflect_row(y0 - 1) * IMW;
        vload(p0, ro, cx0, a0, r3); vload(p1, ro, cx0, a0, g3); vload(p2, ro, cx0, a0, c3b);
    }

    #pragma unroll 1
    for (int k = 0; k < RB + 8; ++k) {
        const int yL = y0 - 4 + k;
        float g[4];
        #pragma unroll
        for (int j = 0; j < 4; ++j)
            g[j] = 0.1495f * r0[j] + 0.2935f * g0[j] + 0.057f * c0b[j];
        // rotate slots (oldest consumed; slot3 freed for refill)
        #pragma unroll
        for (int j = 0; j < 4; ++j) {
            r0[j] = r1[j]; r1[j] = r2[j]; r2[j] = r3[j];
            g0[j] = g1[j]; g1[j] = g2[j]; g2[j] = g3[j];
            c0b[j] = c1b[j]; c1b[j] = c2b[j]; c2b[j] = c3b[j];
        }
        if (k < RB + 4) {   // refill 4 steps ahead of consumption
            int ro = reflect_row(yL + 4) * IMW;
            vload(p0, ro, cx0, a0, r3);
            vload(p1, ro, cx0, a0, g3);
            vload(p2, ro, cx0, a0, c3b);
        }
        // gray + horizontal blur (every step)
        float Lm1 = dpp_shr1(g[3]), Lm2 = dpp_shr1(g[2]);
        float Rp1 = dpp_shl1(g[0]), Rp2 = dpp_shl1(g[1]);
        float hn[4];
        hn[0] = w0 * (Lm2 + g[2]) + w1 * (Lm1 + g[1]) + w2 * g[0];
        hn[1] = w0 * (Lm1 + g[3]) + w1 * (g[0] + g[2]) + w2 * g[1];
        hn[2] = w0 * (g[0] + Rp1) + w1 * (g[1] + g[3]) + w2 * g[2];
        hn[3] = w0 * (g[1] + Rp2) + w1 * (g[2] + Rp1) + w2 * g[3];

        float bn[4] = {0, 0, 0, 0};
        float bnL = 0, bnR = 0;
        if (k >= 4) {            // vertical blur -> row yL-2
            #pragma unroll
            for (int j = 0; j < 4; ++j)
                bn[j] = w0 * (h0[j] + hn[j]) + w1 * (h1[j] + h3[j]) + w2 * h2[j];
            bnL = dpp_shr1(bn[3]); bnR = dpp_shl1(bn[0]);
        }
        float mn[4] = {0, 0, 0, 0}, gxv[4] = {0, 0, 0, 0}, gyv[4] = {0, 0, 0, 0};
        float mnL = 0, mnR = 0;
        if (k >= 6) {            // sobel+mag -> row yL-3
            const int u = yL - 3;
            float ta[4], tb[4], taL, taR, tbL, tbR;
            #pragma unroll
            for (int j = 0; j < 4; ++j) { ta[j] = b1[j]; tb[j] = bn[j]; }
            taL = b1L; taR = b1R; tbL = bnL; tbR = bnR;
            if (u == 0) {        // top edge (band 0 only)
                #pragma unroll
                for (int j = 0; j < 4; ++j) ta[j] = b0[j];
                taL = b0L; taR = b0R;
            }
            if (u == IMH - 1) {  // bottom edge (band NBAND-1 only)
                #pragma unroll
                for (int j = 0; j < 4; ++j) tb[j] = b0[j];
                tbL = b0L; tbR = b0R;
            }
            // sobel EDGE pad at image left: b(-1) := b(0)
            if (clampL) { taL = ta[0]; tbL = tb[0]; }
            const float b0Ledge = clampL ? b0[0] : b0L;
            #pragma unroll
            for (int j = 0; j < 4; ++j) {
                float tla = (j == 0) ? taL : ta[j - 1];
                float tra = (j == 3) ? taR : ta[j + 1];
                float tlb = (j == 0) ? tbL : tb[j - 1];
                float trb = (j == 3) ? tbR : tb[j + 1];
                float bl0 = (j == 0) ? b0Ledge : b0[j - 1];
                float br0 = (j == 3) ? b0R : b0[j + 1];
                gxv[j] = (tra - tla) + 2.0f * (br0 - bl0) + (trb - tlb);
                gyv[j] = (tlb - tla) + 2.0f * (tb[j] - ta[j]) + (trb - tra);
                mn[j] = __builtin_amdgcn_sqrtf(gxv[j] * gxv[j] + gyv[j] * gyv[j] + 1e-6f);
            }
            // NMS ZERO pad at image left: mag(-1) := 0
            if (a0) mn[3] = 0.0f;
            mnL = dpp_shr1(mn[3]); mnR = dpp_shl1(mn[0]);
        }
        if (k >= 8) {            // NMS + store row s = yL-4
            const int s = yL - 4;
            float pm[4], nm[4], pmL, pmR, nmL, nmR;
            #pragma unroll
            for (int j = 0; j < 4; ++j) { pm[j] = m1[j]; nm[j] = mn[j]; }
            pmL = m1L; pmR = m1R; nmL = mnL; nmR = mnR;
            if (s == 0) {
                #pragma unroll
                for (int j = 0; j < 4; ++j) pm[j] = 0.0f;
                pmL = 0.0f; pmR = 0.0f;
            }
            if (s == IMH - 1) {
                #pragma unroll
                for (int j = 0; j < 4; ++j) nm[j] = 0.0f;
                nmL = 0.0f; nmR = 0.0f;
            }
            float o[4];
            #pragma unroll
            for (int j = 0; j < 4; ++j) {
                float pml = (j == 0) ? pmL : pm[j - 1];
                float pmr = (j == 3) ? pmR : pm[j + 1];
                float nml = (j == 0) ? nmL : nm[j - 1];
                float nmr = (j == 3) ? nmR : nm[j + 1];
                float ml0 = (j == 0) ? m0L : m0[j - 1];
                float mr0 = (j == 3) ? m0R : m0[j + 1];
                float ax = fabsf(gxp[j]), ay = fabsf(gyp[j]);
                bool ew = (ay <= 0.41421356237f * ax);
                bool ns = (ay >= 2.41421356237f * ax);
                bool d1 = (gxp[j] * gyp[j] > 0.0f);
                float n1 = ew ? mr0 : (ns ? nm[j] : (d1 ? pmr : nmr));
                float n2 = ew ? ml0 : (ns ? pm[j] : (d1 ? nml : pml));
                float mag = m0[j];
                o[j] = (mag > n1 && mag > n2) ? mag : 0.0f;
            }
            if (storeok) {
                f32x4 v; v.x = o[0]; v.y = o[1]; v.z = o[2]; v.w = o[3];
                __builtin_nontemporal_store(v,
                    reinterpret_cast<f32x4*>(outp + (size_t)s * IMW + cx0));
            }
        }
        // ring shifts
        #pragma unroll
        for (int j = 0; j < 4; ++j) {
            h0[j] = h1[j]; h1[j] = h2[j]; h2[j] = h3[j]; h3[j] = hn[j];
            b1[j] = b0[j]; b0[j] = bn[j];
            m1[j] = m0[j]; m0[j] = mn[j];
            gxp[j] = gxv[j]; gyp[j] = gyv[j];
        }
        b1L = b0L; b1R = b0R; b0L = bnL; b0R = bnR;
        m1L = m0L; m1R = m0R; m0L = mnL; m0R = mnR;
    }
}

// ---------------- scalar path (strip C only: right edge, 64 cols) ------------
__device__ __forceinline__ void run_band_sc(const float* __restrict__ p0,
                                            const float* __restrict__ p1,
                                            const float* __restrict__ p2,
                                            float* __restrict__ outp,
                                            int y0, int c0, int lane) {
    const float w0 = 0.05448868f, w1 = 0.24420134f, w2 = 0.40261995f;
    const int cx = c0 + lane;
    const int rx = reflect_i(cx, IMW);
    const int ixm = ((cx - 1 < 0) ? 0 : (cx - 1 >= IMW ? IMW - 1 : cx - 1)) - c0;
    const int ixp = ((cx + 1 < 0) ? 0 : (cx + 1 >= IMW ? IMW - 1 : cx + 1)) - c0;
    const bool storeok = (lane >= 4) && (lane < 60) && ((unsigned)cx < (unsigned)IMW);

    float h0 = 0, h1 = 0, h2 = 0, h3 = 0;
    float b_1 = 0, b_0 = 0, bl_1 = 0, bl_0 = 0, br_1 = 0, br_0 = 0;
    float m_1 = 0, m_0 = 0, ml_1 = 0, ml_0 = 0, mr_1 = 0, mr_0 = 0;
    float gxp = 0, gyp = 0;

    // depth-4 rotated slots
    float pr0, pr1, pr2, pr3, pg0, pg1, pg2, pg3, pb0, pb1, pb2, pb3;
    {
        int yo;
        yo = reflect_row(y0 - 4) * IMW + rx; pr0 = p0[yo]; pg0 = p1[yo]; pb0 = p2[yo];
        yo = reflect_row(y0 - 3) * IMW + rx; pr1 = p0[yo]; pg1 = p1[yo]; pb1 = p2[yo];
        yo = reflect_row(y0 - 2) * IMW + rx; pr2 = p0[yo]; pg2 = p1[yo]; pb2 = p2[yo];
        yo = reflect_row(y0 - 1) * IMW + rx; pr3 = p0[yo]; pg3 = p1[yo]; pb3 = p2[yo];
    }

    #pragma unroll 1
    for (int k = 0; k < RB + 8; ++k) {
        const int yL = y0 - 4 + k;
        float gray = 0.1495f * pr0 + 0.2935f * pg0 + 0.057f * pb0;
        pr0 = pr1; pr1 = pr2; pr2 = pr3;
        pg0 = pg1; pg1 = pg2; pg2 = pg3;
        pb0 = pb1; pb1 = pb2; pb2 = pb3;
        if (k < RB + 4) {
            int yo = reflect_row(yL + 4) * IMW + rx;
            pr3 = p0[yo]; pg3 = p1[yo]; pb3 = p2[yo];
        }
        float gm1 = dpp_shr1(gray);
        float gm2 = dpp_shr1(gm1);
        float gp1 = dpp_shl1(gray);
        float gp2 = dpp_shl1(gp1);
        float hnew = w0 * (gm2 + gp2) + w1 * (gm1 + gp1) + w2 * gray;

        float bnew = 0, blnew = 0, brnew = 0;
        if (k >= 4) {
            bnew = w0 * (h0 + hnew) + w1 * (h1 + h3) + w2 * h2;
            blnew = __shfl(bnew, ixm); brnew = __shfl(bnew, ixp);
        }

        float mnew = 0, mlnew = 0, mrnew = 0, gx = 0, gy = 0;
        if (k >= 6) {
            int u = yL - 3;
            float ta = b_1, tla = bl_1, tra = br_1;
            float tb = bnew, tlb = blnew, trb = brnew;
            if (u == 0)       { ta = b_0; tla = bl_0; tra = br_0; }
            if (u == IMH - 1) { tb = b_0; tlb = bl_0; trb = br_0; }
            gx = (tra - tla) + 2.0f * (br_0 - bl_0) + (trb - tlb);
            gy = (tlb - tla) + 2.0f * (tb - ta) + (trb - tra);
            mnew = __builtin_amdgcn_sqrtf(gx * gx + gy * gy + 1e-6f);
            if ((unsigned)cx >= (unsigned)IMW) mnew = 0.0f;
            mlnew = dpp_shr1(mnew);
            mrnew = dpp_shl1(mnew);
        }

        if (k >= 8) {
            int s = yL - 4;
            float pm = m_1, pml = ml_1, pmr = mr_1;
            float nm = mnew, nml = mlnew, nmr = mrnew;
            if (s == 0)       { pm = 0; pml = 0; pmr = 0; }
            if (s == IMH - 1) { nm = 0; nml = 0; nmr = 0; }
            float ax = fabsf(gxp), ay = fabsf(gyp);
            bool ew = (ay <= 0.41421356237f * ax);
            bool ns = (ay >= 2.41421356237f * ax);
            bool d1 = (gxp * gyp > 0.0f);
            float n1 = ew ? mr_0 : (ns ? nm : (d1 ? pmr : nmr));
            float n2 = ew ? ml_0 : (ns ? pm : (d1 ? nml : pml));
            float mag = m_0;
            float o = (mag > n1 && mag > n2) ? mag : 0.0f;
            if (storeok)
                __builtin_nontemporal_store(o, &outp[(size_t)s * IMW + cx]);
        }

        h0 = h1; h1 = h2; h2 = h3; h3 = hnew;
        b_1 = b_0;  b_0 = bnew;
        bl_1 = bl_0; bl_0 = blnew;
        br_1 = br_0; br_0 = brnew;
        m_1 = m_0;  m_0 = mnew;
        ml_1 = ml_0; ml_0 = mlnew;
        mr_1 = mr_0; mr_0 = mrnew;
        gxp = gx; gyp = gy;
    }
}

__global__ __launch_bounds__(256, 2)
void canny_stream(const float* __restrict__ data, float* __restrict__ out) {
    const int lane = threadIdx.x & 63;
    // XCD-aware swizzle: blocks with equal blockIdx%8 -> one XCD;
    // each XCD owns 2 batches walked band-sequentially for L2 halo hits.
    // waves: (bat) x (band 0..63) x (strip 0..2); 3072 waves = 768 blocks.
    const int xcd = blockIdx.x & 7;
    const int seq = blockIdx.x >> 3;               // 0..95
    const int lw  = seq * 4 + (threadIdx.x >> 6);  // 0..383 within XCD
    const int strip = lw % 3;
    const int t = lw / 3;                          // 0..127
    const int band = t & (NBAND - 1);
    const int bat = (xcd << 1) | (t >> 6);
    const int y0 = band * RB;

    const size_t plane = (size_t)(IMH * IMW);
    const float* p0 = data + (size_t)bat * 3 * plane;
    const float* p1 = p0 + plane;
    const float* p2 = p1 + plane;
    float* outp = out + (size_t)bat * plane;

    if (strip == 2) {
        run_band_sc(p0, p1, p2, outp, y0, 488, lane);          // out 492..511
    } else {
        // single call site -> single code copy for both vec4 strips
        const bool isA = (strip == 0);
        const int c0 = isA ? -4 : 244;
        run_band_v4(p0, p1, p2, outp, y0, c0, lane, isA);      // out 0..491
    }
}

extern "C" void kernel_launch(void* const* d_in, const int* in_sizes, int n_in,
                              void* d_out, int out_size, void* d_ws, size_t ws_size,
                              hipStream_t stream) {
    const float* data = (const float*)d_in[0];
    float* out = (float*)d_out;
    int B = in_sizes[0] / (3 * IMH * IMW);       // 16
    int blocks = (B * NBAND * 3) / 4;            // 768 blocks, 3072 waves
    canny_stream<<<blocks, dim3(256, 1, 1), 0, stream>>>(data, out);
}